// Round 15
// baseline (560.905 us; speedup 1.0000x reference)
//
#include <hip/hip_runtime.h>

// B=8, S=1024, MD=1024, H=16, D=64. SCALE = (64//16)^-0.5 = 0.5.
// Inputs fp32, OUTPUTS fp32. Internal pipeline bf16 MFMA, fp32 accumulate.
// torch .view(B*H,-1,D) = flat row-major reinterpretation: attention over
// [G=128][T=1024][D=64] with flat pointer math.
//
// R14->R15: R14's occupancy stayed 11% -- 66.5KB LDS still rounds to 1
// block/CU (empirical table: 17KB->4, 34KB->2, 50KB->2, 66KB->1). The
// inter-block-TLP-at-CONSTANT-VMEM-density experiment has never actually
// run. This round: s processed in 4 chunks of 256 with exact online
// accumulation (deferred norm => no rescale), shrinking Plds to [32][264]
// = 16.9KB (+1KB dbuf'd red) => 2 blocks/CU truly resident at R9's exact
// per-wave VMEM density. Cost: 9 barriers/head vs 2 (~+5-10us known).
// Fragment math, load counts, MFMA counts byte-identical to R9/R14.

typedef __attribute__((ext_vector_type(8))) short bf16x8;
typedef __attribute__((ext_vector_type(4))) float f32x4;

static __device__ __forceinline__ short f2bf(float f) {
  union { float f; unsigned u; } v; v.f = f;
  unsigned lsb = (v.u >> 16) & 1u;
  v.u += 0x7fffu + lsb;
  return (short)(v.u >> 16);
}

static __device__ __forceinline__ float bf2f(short s) {
  union { float f; unsigned u; } v;
  v.u = ((unsigned)(unsigned short)s) << 16;
  return v.f;
}

// round-half-up bf16 (2 ops); fine for positive e^x values
static __device__ __forceinline__ short f2bf_rhu(float f) {
  union { float f; unsigned u; } v; v.f = f;
  v.u += 0x8000u;
  return (short)(v.u >> 16);
}

// hardware 2^x
static __device__ __forceinline__ float exp2_hw(float x) {
  float r;
  asm("v_exp_f32 %0, %1" : "=v"(r) : "v"(x));
  return r;
}

#define L2E_HALF 0.72134752f   /* 0.5 * log2(e) : e^(score*0.5) = 2^(score*this) */

// async global->LDS, 16B per lane; LDS dest = wave-uniform base + lane*16
#define GLDS16(gp, lp) __builtin_amdgcn_global_load_lds( \
    (const __attribute__((address_space(1))) void*)(gp), \
    (__attribute__((address_space(3))) void*)(lp), 16, 0, 0)

struct Ptr4 { const float* s[4]; short* d[4]; };
struct Ptr3 { const float* s[3]; short* d[3]; };
struct QkvArgs { const short* A[3]; const short* B[3]; const float* bias[3]; short* C[3]; };

// ---------- fp32 W[k][n] -> bf16 WT[n][k], 64x64 tiles; z selects matrix ----
__global__ __launch_bounds__(256) void convt4(Ptr4 a)
{
  const float* __restrict__ src = a.s[blockIdx.z];
  short* __restrict__ dst = a.d[blockIdx.z];
  __shared__ float T[64][65];
  const int tid = threadIdx.x;
  const int c0 = blockIdx.x * 64, r0 = blockIdx.y * 64;
  {
    const int rr = tid >> 4, cc = (tid & 15) * 4;
    for (int i = 0; i < 4; ++i) {
      int row = rr + i * 16;
      const float4 v = *(const float4*)(src + (size_t)(r0 + row) * 1024 + c0 + cc);
      T[row][cc] = v.x; T[row][cc + 1] = v.y; T[row][cc + 2] = v.z; T[row][cc + 3] = v.w;
    }
  }
  __syncthreads();
  {
    const int rr = tid >> 3, cc = (tid & 7) * 8;
    for (int i = 0; i < 2; ++i) {
      int row = rr + i * 32;             // dst row within tile (= src col)
      bf16x8 v;
      for (int j = 0; j < 8; ++j) v[j] = f2bf(T[cc + j][row]);
      *(bf16x8*)(dst + (size_t)(c0 + row) * 1024 + r0 + cc) = v;
    }
  }
}

// ---------- fp32 -> bf16 elementwise; z selects tensor ----------
__global__ __launch_bounds__(256) void cvt3(Ptr3 a)
{
  const float* __restrict__ src = a.s[blockIdx.z];
  short* __restrict__ dst = a.d[blockIdx.z];
  const size_t i = ((size_t)blockIdx.x * 256 + threadIdx.x) * 8;
  const float4 v0 = *(const float4*)(src + i);
  const float4 v1 = *(const float4*)(src + i + 4);
  bf16x8 o;
  o[0] = f2bf(v0.x); o[1] = f2bf(v0.y); o[2] = f2bf(v0.z); o[3] = f2bf(v0.w);
  o[4] = f2bf(v1.x); o[5] = f2bf(v1.y); o[6] = f2bf(v1.z); o[7] = f2bf(v1.w);
  *(bf16x8*)(dst + i) = o;
}

// ---------- attn_post finalize: ap += upcast(part)  (8M elems) ----------
__global__ __launch_bounds__(256) void add_post(
    float* __restrict__ ap, const short* __restrict__ part)
{
  const size_t i = ((size_t)blockIdx.x * 256 + threadIdx.x) * 8;
  float4 a0 = *(float4*)(ap + i);
  float4 a1 = *(float4*)(ap + i + 4);
  const bf16x8 p = *(const bf16x8*)(part + i);
  a0.x += bf2f(p[0]); a0.y += bf2f(p[1]); a0.z += bf2f(p[2]); a0.w += bf2f(p[3]);
  a1.x += bf2f(p[4]); a1.y += bf2f(p[5]); a1.z += bf2f(p[6]); a1.w += bf2f(p[7]);
  *(float4*)(ap + i) = a0;
  *(float4*)(ap + i + 4) = a1;
}

// ---------- per-g 64x64 bf16 tile transpose: V[g][t][d] -> VpT[g][d][t] ----
__global__ __launch_bounds__(256) void transp_v(
    const short* __restrict__ src, short* __restrict__ dst)
{
  __shared__ short T[64][72];
  const int g = blockIdx.y, t0 = blockIdx.x * 64;
  const short* s = src + (size_t)g * 65536 + (size_t)t0 * 64;
  short* d = dst + (size_t)g * 65536 + t0;
  const int r = threadIdx.x >> 3, c = (threadIdx.x & 7) * 8;
  for (int i = 0; i < 2; ++i) {
    bf16x8 v = *(const bf16x8*)(s + (size_t)(r + i * 32) * 64 + c);
    *(bf16x8*)(&T[r + i * 32][c]) = v;
  }
  __syncthreads();
  for (int i = 0; i < 2; ++i) {
    int dr = r + i * 32;                 // d index
    bf16x8 v;
    for (int j = 0; j < 8; ++j) v[j] = T[c + j][dr];
    *(bf16x8*)(d + (size_t)dr * 1024 + c) = v;
  }
}

// ---------- GEMM body: C[8192,1024] = A[8192,1024](bf16) * BT[1024,1024]^T + bias
// R12 config kept: 128x128 tiles, 512 blocks, M-panel XCD swizzle,
// 2-phase dbuf pipeline (stage t+1 before compute t, one barrier/k-step).
static __device__ __forceinline__ void gemm_body(
    const short* __restrict__ A, const short* __restrict__ BT,
    const float* __restrict__ bias, void* __restrict__ Cp, int mode)
{
  __shared__ short As[2][128 * 64];
  __shared__ short Bs[2][128 * 64];
  const int K = 1024, N = 1024;
  const int tid = threadIdx.x;
  const int lane = tid & 63, wave = tid >> 6;
  const int quad = lane >> 4, l16 = lane & 15;
  const int wm = (wave & 1) * 64, wn = (wave >> 1) * 64;
  const int lin = blockIdx.y * 64 + blockIdx.x;
  const int xcd = lin & 7, idx = lin >> 3;       // idx 0..63
  const int bx = xcd * 8 + (idx & 7);            // M-tile 0..63
  const int by = idx >> 3;                       // N-tile 0..7
  const int bm = bx * 128, bn = by * 128;

  f32x4 acc[4][4] = {};

  const int s_row = tid >> 3;            // 0..31
  const int s_col = (tid & 7) * 8;       // 0..56 (shorts)
  const int lds_base = wave * 512;       // wave-uniform (shorts)

  // prologue: stage k0=0 into buffer 0
  for (int i = 0; i < 4; ++i) {
    int row = s_row + i * 32;
    GLDS16(A + (size_t)(bm + row) * K + s_col, &As[0][i * 2048 + lds_base]);
    GLDS16(BT + (size_t)(bn + row) * K + s_col, &Bs[0][i * 2048 + lds_base]);
  }
  __syncthreads();                       // drains prologue stage

  int cur = 0;
  for (int t = 0; t < 16; ++t) {
    // stage NEXT k-tile first (loads fly during compute below)
    if (t < 15) {
      const int k0 = (t + 1) * 64;
      for (int i = 0; i < 4; ++i) {
        int row = s_row + i * 32;
        GLDS16(A + (size_t)(bm + row) * K + k0 + s_col, &As[cur ^ 1][i * 2048 + lds_base]);
        GLDS16(BT + (size_t)(bn + row) * K + k0 + s_col, &Bs[cur ^ 1][i * 2048 + lds_base]);
      }
    }
    // compute current tile
    for (int ks = 0; ks < 2; ++ks) {
      bf16x8 af[4], bfr[4];
      for (int mi = 0; mi < 4; ++mi)
        af[mi] = *(const bf16x8*)(&As[cur][(wm + mi * 16 + l16) * 64 + ks * 32 + quad * 8]);
      for (int ni = 0; ni < 4; ++ni)
        bfr[ni] = *(const bf16x8*)(&Bs[cur][(wn + ni * 16 + l16) * 64 + ks * 32 + quad * 8]);
      for (int mi = 0; mi < 4; ++mi)
        for (int ni = 0; ni < 4; ++ni)
          acc[mi][ni] = __builtin_amdgcn_mfma_f32_16x16x32_bf16(af[mi], bfr[ni], acc[mi][ni], 0, 0, 0);
    }
    __syncthreads();                     // drains next-tile stage; guards buffer reuse
    cur ^= 1;
  }

  for (int ni = 0; ni < 4; ++ni) {
    int col = bn + wn + ni * 16 + l16;
    float bv = bias[col];
    for (int mi = 0; mi < 4; ++mi) {
      int row0 = bm + wm + mi * 16 + quad * 4;   // C row = quad*4+reg
      for (int r = 0; r < 4; ++r) {
        int row = row0 + r;
        float fv = acc[mi][ni][r] + bv;
        if (mode == 2) ((float*)Cp)[(size_t)row * N + col] = fv;
        else           ((short*)Cp)[(size_t)row * N + col] = f2bf(fv);
      }
    }
  }
}

__global__ __launch_bounds__(256) void gemm_bt16(
    const short* __restrict__ A, const short* __restrict__ BT,
    const float* __restrict__ bias, void* __restrict__ Cp, int mode)
{
  gemm_body(A, BT, bias, Cp, mode);
}

// combined Q/K/V projection: grid.z selects which GEMM
__global__ __launch_bounds__(256) void gemm_qkv(QkvArgs a)
{
  const int z = blockIdx.z;
  gemm_body(a.A[z], a.B[z], a.bias[z], a.C[z], 0);
}

// ---------- fused attention over [G=128,T=1024,D=64] ----------
// s-CHUNKED (4 x 256) with exact online accumulation: Plds shrinks to
// [32][264] = 16.9KB so 2 blocks/CU are truly co-resident (first clean
// inter-block TLP test at R9's per-wave VMEM density). block = (b, hg of
// 8 heads, 32-row t-tile); grid 512. Per chunk: 4 waves score 64-wide
// s-strips (raw e^x -> Plds, deferred norm) | B1 | d-split PV (wave owns
// 16 d-cols) accumulates across chunks | B2. After 4 chunks: rsum reduce
// via dbuf'd red | B3 | scale + ctx write. Epilogue: hg0 -> f32
// attn_post; hg1 -> bf16 partial (add_post sums). No atomics.
__global__ __launch_bounds__(256, 1) void attn_fused13(
    const short* __restrict__ Qp, const short* __restrict__ Kp,
    const short* __restrict__ VpT,               // [g][d][t]
    short* __restrict__ ctx,                     // [g][t][d] flat (bf16)
    float* __restrict__ attn_post,               // [b][t][s] FP32 (hg0 partial)
    short* __restrict__ part)                    // [b][t][s] bf16 (hg1 partial)
{
  __shared__ short Plds[32][264];                // 16.9KB (chunk of 256 + pad)
  __shared__ float red[2][32][4];                // dbuf'd by head parity

  const int tid = threadIdx.x;
  const int wave = tid >> 6, lane = tid & 63;
  const int quad = lane >> 4, l16 = lane & 15;
  // XCD-chunk remap (T1): b == orig&7  (XCD i <- batch i)
  const int orig = blockIdx.x;                   // 0..511
  const int b = orig & 7;
  const int hg = (orig >> 3) & 1;                // head group (8 heads)
  const int t0 = (orig >> 4) * 32;               // 32-row t-tile
  const int wbase = wave * 64;                   // wave's strip within a chunk

  float sig[2][16][4] = {};                      // [tt][c*4+tile][r], 8-head sum

  for (int h = hg * 8; h < hg * 8 + 8; ++h) {
    const int g = b * 16 + h;
    const short* Qg = Qp + (size_t)g * 65536;
    const short* Kg = Kp + (size_t)g * 65536;
    const short* Vg = VpT + (size_t)g * 65536;
    const short* Vw = Vg + (size_t)(wave * 16 + l16) * 1024;

    bf16x8 aq[2][2];
#pragma unroll
    for (int tt = 0; tt < 2; ++tt) {
      aq[tt][0] = *(const bf16x8*)(Qg + (t0 + tt * 16 + l16) * 64 + quad * 8);
      aq[tt][1] = *(const bf16x8*)(Qg + (t0 + tt * 16 + l16) * 64 + 32 + quad * 8);
    }

    float rsum[2][4] = {};
    f32x4 acc[2][2] = {};                        // PV accumulators, [tt][parity]

#pragma unroll
    for (int c = 0; c < 4; ++c) {
      const int sb = c * 256 + wbase;            // wave's 64-wide strip

      // ---- score: 4 s-tiles, all K fragments preloaded ----
      bf16x8 kb0[4], kb1[4];
#pragma unroll
      for (int t = 0; t < 4; ++t) {
        int s = sb + t * 16;
        kb0[t] = *(const bf16x8*)(Kg + (s + l16) * 64 + quad * 8);
        kb1[t] = *(const bf16x8*)(Kg + (s + l16) * 64 + 32 + quad * 8);
      }
#pragma unroll
      for (int tile = 0; tile < 4; ++tile) {
#pragma unroll
        for (int tt = 0; tt < 2; ++tt) {
          f32x4 cc = {0.f, 0.f, 0.f, 0.f};
          cc = __builtin_amdgcn_mfma_f32_16x16x32_bf16(aq[tt][0], kb0[tile], cc, 0, 0, 0);
          cc = __builtin_amdgcn_mfma_f32_16x16x32_bf16(aq[tt][1], kb1[tile], cc, 0, 0, 0);
#pragma unroll
          for (int r = 0; r < 4; ++r) {
            float e = exp2_hw(cc[r] * L2E_HALF);  // e^(score*0.5)
            rsum[tt][r] += e;
            Plds[tt * 16 + quad * 4 + r][wbase + tile * 16 + l16] = f2bf_rhu(e);
            sig[tt][c * 4 + tile][r] += e * __builtin_amdgcn_rcpf(1.f + e);
          }
        }
      }
      __syncthreads();                           // B1: chunk's Plds ready

      // ---- PV for this chunk: wave owns d-cols [wave*16,+16) ----
#pragma unroll
      for (int sl = 0; sl < 8; ++sl) {
        bf16x8 v  = *(const bf16x8*)(Vw + c * 256 + sl * 32 + quad * 8);
        bf16x8 p0 = *(const bf16x8*)(&Plds[l16][sl * 32 + quad * 8]);
        bf16x8 p1 = *(const bf16x8*)(&Plds[16 + l16][sl * 32 + quad * 8]);
        acc[0][sl & 1] = __builtin_amdgcn_mfma_f32_16x16x32_bf16(p0, v, acc[0][sl & 1], 0, 0, 0);
        acc[1][sl & 1] = __builtin_amdgcn_mfma_f32_16x16x32_bf16(p1, v, acc[1][sl & 1], 0, 0, 0);
      }
      __syncthreads();                           // B2: Plds free for next chunk
    }

    // ---- rowsum reduce + normalize + ctx write ----
#pragma unroll
    for (int tt = 0; tt < 2; ++tt)
      for (int r = 0; r < 4; ++r)
        for (int mask = 1; mask < 16; mask <<= 1)
          rsum[tt][r] += __shfl_xor(rsum[tt][r], mask, 64);
    if (l16 == 0)
#pragma unroll
      for (int tt = 0; tt < 2; ++tt)
        for (int r = 0; r < 4; ++r)
          red[h & 1][tt * 16 + quad * 4 + r][wave] = rsum[tt][r];
    __syncthreads();                             // B3: red visible

    short* ctxg = ctx + (size_t)g * 65536 + t0 * 64;
#pragma unroll
    for (int tt = 0; tt < 2; ++tt)
      for (int r = 0; r < 4; ++r) {
        int row = tt * 16 + quad * 4 + r;
        float s4 = red[h & 1][row][0] + red[h & 1][row][1]
                 + red[h & 1][row][2] + red[h & 1][row][3];
        float inv = __builtin_amdgcn_rcpf(s4);
        float cval = (acc[tt][0][r] + acc[tt][1][r]) * inv;
        ctxg[row * 64 + wave * 16 + l16] = f2bf(cval);
      }
    // next head's Plds writes are separated from this head's PV reads by
    // B2(c=3)+B3; red is parity-double-buffered -> no extra barrier.
  }

  // epilogue: disjoint plain stores (no atomics, no RMW)
  if (hg == 0) {
    float* ap_out = attn_post + (size_t)b * 1048576 + (size_t)t0 * 1024;
#pragma unroll
    for (int tt = 0; tt < 2; ++tt)
      for (int k = 0; k < 16; ++k) {
        int ci = k >> 2, tile = k & 3;
        for (int r = 0; r < 4; ++r)
          ap_out[(tt * 16 + quad * 4 + r) * 1024 + ci * 256 + wbase + tile * 16 + l16] =
              sig[tt][k][r] * 0.0625f;
      }
  } else {
    short* pp = part + (size_t)b * 1048576 + (size_t)t0 * 1024;
#pragma unroll
    for (int tt = 0; tt < 2; ++tt)
      for (int k = 0; k < 16; ++k) {
        int ci = k >> 2, tile = k & 3;
        for (int r = 0; r < 4; ++r)
          pp[(tt * 16 + quad * 4 + r) * 1024 + ci * 256 + wbase + tile * 16 + l16] =
              f2bf(sig[tt][k][r] * 0.0625f);
      }
  }
}

extern "C" void kernel_launch(void* const* d_in, const int* in_sizes, int n_in,
                              void* d_out, int out_size, void* d_ws, size_t ws_size,
                              hipStream_t stream) {
  const float* query = (const float*)d_in[0];
  const float* key   = (const float*)d_in[1];
  const float* value = (const float*)d_in[2];
  const float* Wq = (const float*)d_in[3]; const float* bq = (const float*)d_in[4];
  const float* Wk = (const float*)d_in[5]; const float* bk = (const float*)d_in[6];
  const float* Wv = (const float*)d_in[7]; const float* bv = (const float*)d_in[8];
  const float* Wo = (const float*)d_in[9]; const float* bo = (const float*)d_in[10];

  float* out0 = (float*)d_out;              // [8,1024,1024] fp32
  float* attn_post = out0 + (8u << 20);     // [8,1024,1024] fp32

  // common workspace head: 4 x 1M weightT + 3 x 8M (Qp,Kp,VpT)
  short* WqT = (short*)d_ws;
  short* WkT = WqT + (1u << 20);
  short* WvT = WkT + (1u << 20);
  short* WoT = WvT + (1u << 20);
  short* Qp  = WoT + (1u << 20);
  short* Kp  = Qp + (8u << 20);
  short* VpT = Kp + (8u << 20);

  dim3 blk(256);
  dim3 ggrid(64, 8);                        // 512 blocks, 128x128 tiles
  const size_t NEED_BIG = (size_t)(60u << 20) * 2;   // 120 MiB

  convt4<<<dim3(16, 16, 4), blk, 0, stream>>>(
      Ptr4{{Wq, Wk, Wv, Wo}, {WqT, WkT, WvT, WoT}});

  short* ctx;
  short* part;                              // bf16 hg1 sigmoid partial (16 MB)
  if (ws_size >= NEED_BIG) {
    // big layout: + Xq,Xk,Xv (3 x 8M) + Vflat (8M) = 60M shorts total
    short* Xq = VpT + (8u << 20);
    short* Xk = Xq + (8u << 20);
    short* Xv = Xk + (8u << 20);
    short* Vflat = Xv + (8u << 20);
    ctx = Xq;                                      // dead after qkv GEMM
    part = Vflat;                                  // dead after transp_v

    cvt3<<<dim3(4096, 1, 3), blk, 0, stream>>>(Ptr3{{query, key, value}, {Xq, Xk, Xv}});
    gemm_qkv<<<dim3(64, 8, 3), blk, 0, stream>>>(
        QkvArgs{{Xq, Xk, Xv}, {WqT, WkT, WvT}, {bq, bk, bv}, {Qp, Kp, Vflat}});
    transp_v<<<dim3(16, 128), blk, 0, stream>>>(Vflat, VpT);
  } else {
    // small layout (88 MB, proven): Xin (8M) + Vflat (8M), sequential
    short* Xin = VpT + (8u << 20);
    short* Vflat = Xin + (8u << 20);
    ctx = Xin;
    part = Vflat;                                  // dead after transp_v

    cvt3<<<dim3(4096, 1, 1), blk, 0, stream>>>(Ptr3{{query, query, query}, {Xin, Xin, Xin}});
    gemm_bt16<<<ggrid, blk, 0, stream>>>(Xin, WqT, bq, Qp, 0);
    cvt3<<<dim3(4096, 1, 1), blk, 0, stream>>>(Ptr3{{key, key, key}, {Xin, Xin, Xin}});
    gemm_bt16<<<ggrid, blk, 0, stream>>>(Xin, WkT, bk, Kp, 0);
    cvt3<<<dim3(4096, 1, 1), blk, 0, stream>>>(Ptr3{{value, value, value}, {Xin, Xin, Xin}});
    gemm_bt16<<<ggrid, blk, 0, stream>>>(Xin, WvT, bv, Vflat, 0);
    transp_v<<<dim3(16, 128), blk, 0, stream>>>(Vflat, VpT);
  }

  attn_fused13<<<dim3(512), blk, 0, stream>>>(Qp, Kp, VpT, ctx, attn_post, part);
  add_post<<<dim3(4096), blk, 0, stream>>>(attn_post, part);
  gemm_bt16<<<ggrid, blk, 0, stream>>>(ctx, WoT, bo, out0, 2);
}

// Round 16
// 478.711 us; speedup vs baseline: 1.1717x; 1.1717x over previous
//
#include <hip/hip_runtime.h>

// B=8, S=1024, MD=1024, H=16, D=64. SCALE = (64//16)^-0.5 = 0.5.
// Inputs fp32, OUTPUTS fp32. Internal pipeline bf16 MFMA, fp32 accumulate.
// torch .view(B*H,-1,D) = flat row-major reinterpretation: attention over
// [G=128][T=1024][D=64] with flat pointer math.
//
// R15->R16: R15 (17.9KB LDS, occ still 11.6%, VGPR 176) exposed the real
// occupancy limiter: UNIFIED register file (~176 arch + ~120 AGPR for the
// 128-float sig accumulator ~= 300/wave -> 1 wave/SIMD always). All prior
// "TLP tests" were register-blocked; R13's cap spilled because demand>256.
// This round hits the one untested config: (a) sig packed f16 (h2 pairs,
// -64 regs -> demand ~230 fits a (256,2) cap w/o spill; f16 sig proven in
// R3), (b) s in 2 chunks of 512 -> Plds[32][520]=33.3KB (R2/R3's exact
// footprint, measured 2 blocks/CU), (c) hg-split grid 512. 8-tile loops
// with 4-deep K prefetch ~= R9 per-wave efficiency. Diagnostic: spill
// shows as FETCH >> 41MB (voids the result).

typedef __attribute__((ext_vector_type(8))) short bf16x8;
typedef __attribute__((ext_vector_type(4))) float f32x4;
typedef __attribute__((ext_vector_type(2))) _Float16 h2;

static __device__ __forceinline__ short f2bf(float f) {
  union { float f; unsigned u; } v; v.f = f;
  unsigned lsb = (v.u >> 16) & 1u;
  v.u += 0x7fffu + lsb;
  return (short)(v.u >> 16);
}

static __device__ __forceinline__ float bf2f(short s) {
  union { float f; unsigned u; } v;
  v.u = ((unsigned)(unsigned short)s) << 16;
  return v.f;
}

// round-half-up bf16 (2 ops); fine for positive e^x values
static __device__ __forceinline__ short f2bf_rhu(float f) {
  union { float f; unsigned u; } v; v.f = f;
  v.u += 0x8000u;
  return (short)(v.u >> 16);
}

// hardware 2^x
static __device__ __forceinline__ float exp2_hw(float x) {
  float r;
  asm("v_exp_f32 %0, %1" : "=v"(r) : "v"(x));
  return r;
}

#define L2E_HALF 0.72134752f   /* 0.5 * log2(e) : e^(score*0.5) = 2^(score*this) */

// async global->LDS, 16B per lane; LDS dest = wave-uniform base + lane*16
#define GLDS16(gp, lp) __builtin_amdgcn_global_load_lds( \
    (const __attribute__((address_space(1))) void*)(gp), \
    (__attribute__((address_space(3))) void*)(lp), 16, 0, 0)

struct Ptr4 { const float* s[4]; short* d[4]; };
struct Ptr3 { const float* s[3]; short* d[3]; };
struct QkvArgs { const short* A[3]; const short* B[3]; const float* bias[3]; short* C[3]; };

// ---------- fp32 W[k][n] -> bf16 WT[n][k], 64x64 tiles; z selects matrix ----
__global__ __launch_bounds__(256) void convt4(Ptr4 a)
{
  const float* __restrict__ src = a.s[blockIdx.z];
  short* __restrict__ dst = a.d[blockIdx.z];
  __shared__ float T[64][65];
  const int tid = threadIdx.x;
  const int c0 = blockIdx.x * 64, r0 = blockIdx.y * 64;
  {
    const int rr = tid >> 4, cc = (tid & 15) * 4;
    for (int i = 0; i < 4; ++i) {
      int row = rr + i * 16;
      const float4 v = *(const float4*)(src + (size_t)(r0 + row) * 1024 + c0 + cc);
      T[row][cc] = v.x; T[row][cc + 1] = v.y; T[row][cc + 2] = v.z; T[row][cc + 3] = v.w;
    }
  }
  __syncthreads();
  {
    const int rr = tid >> 3, cc = (tid & 7) * 8;
    for (int i = 0; i < 2; ++i) {
      int row = rr + i * 32;             // dst row within tile (= src col)
      bf16x8 v;
      for (int j = 0; j < 8; ++j) v[j] = f2bf(T[cc + j][row]);
      *(bf16x8*)(dst + (size_t)(c0 + row) * 1024 + r0 + cc) = v;
    }
  }
}

// ---------- fp32 -> bf16 elementwise; z selects tensor ----------
__global__ __launch_bounds__(256) void cvt3(Ptr3 a)
{
  const float* __restrict__ src = a.s[blockIdx.z];
  short* __restrict__ dst = a.d[blockIdx.z];
  const size_t i = ((size_t)blockIdx.x * 256 + threadIdx.x) * 8;
  const float4 v0 = *(const float4*)(src + i);
  const float4 v1 = *(const float4*)(src + i + 4);
  bf16x8 o;
  o[0] = f2bf(v0.x); o[1] = f2bf(v0.y); o[2] = f2bf(v0.z); o[3] = f2bf(v0.w);
  o[4] = f2bf(v1.x); o[5] = f2bf(v1.y); o[6] = f2bf(v1.z); o[7] = f2bf(v1.w);
  *(bf16x8*)(dst + i) = o;
}

// ---------- attn_post finalize: ap += upcast(part)  (8M elems) ----------
__global__ __launch_bounds__(256) void add_post(
    float* __restrict__ ap, const short* __restrict__ part)
{
  const size_t i = ((size_t)blockIdx.x * 256 + threadIdx.x) * 8;
  float4 a0 = *(float4*)(ap + i);
  float4 a1 = *(float4*)(ap + i + 4);
  const bf16x8 p = *(const bf16x8*)(part + i);
  a0.x += bf2f(p[0]); a0.y += bf2f(p[1]); a0.z += bf2f(p[2]); a0.w += bf2f(p[3]);
  a1.x += bf2f(p[4]); a1.y += bf2f(p[5]); a1.z += bf2f(p[6]); a1.w += bf2f(p[7]);
  *(float4*)(ap + i) = a0;
  *(float4*)(ap + i + 4) = a1;
}

// ---------- per-g 64x64 bf16 tile transpose: V[g][t][d] -> VpT[g][d][t] ----
__global__ __launch_bounds__(256) void transp_v(
    const short* __restrict__ src, short* __restrict__ dst)
{
  __shared__ short T[64][72];
  const int g = blockIdx.y, t0 = blockIdx.x * 64;
  const short* s = src + (size_t)g * 65536 + (size_t)t0 * 64;
  short* d = dst + (size_t)g * 65536 + t0;
  const int r = threadIdx.x >> 3, c = (threadIdx.x & 7) * 8;
  for (int i = 0; i < 2; ++i) {
    bf16x8 v = *(const bf16x8*)(s + (size_t)(r + i * 32) * 64 + c);
    *(bf16x8*)(&T[r + i * 32][c]) = v;
  }
  __syncthreads();
  for (int i = 0; i < 2; ++i) {
    int dr = r + i * 32;                 // d index
    bf16x8 v;
    for (int j = 0; j < 8; ++j) v[j] = T[c + j][dr];
    *(bf16x8*)(d + (size_t)dr * 1024 + c) = v;
  }
}

// ---------- GEMM body: C[8192,1024] = A[8192,1024](bf16) * BT[1024,1024]^T + bias
// R12 config kept: 128x128 tiles, 512 blocks, M-panel XCD swizzle,
// 2-phase dbuf pipeline (stage t+1 before compute t, one barrier/k-step).
static __device__ __forceinline__ void gemm_body(
    const short* __restrict__ A, const short* __restrict__ BT,
    const float* __restrict__ bias, void* __restrict__ Cp, int mode)
{
  __shared__ short As[2][128 * 64];
  __shared__ short Bs[2][128 * 64];
  const int K = 1024, N = 1024;
  const int tid = threadIdx.x;
  const int lane = tid & 63, wave = tid >> 6;
  const int quad = lane >> 4, l16 = lane & 15;
  const int wm = (wave & 1) * 64, wn = (wave >> 1) * 64;
  const int lin = blockIdx.y * 64 + blockIdx.x;
  const int xcd = lin & 7, idx = lin >> 3;       // idx 0..63
  const int bx = xcd * 8 + (idx & 7);            // M-tile 0..63
  const int by = idx >> 3;                       // N-tile 0..7
  const int bm = bx * 128, bn = by * 128;

  f32x4 acc[4][4] = {};

  const int s_row = tid >> 3;            // 0..31
  const int s_col = (tid & 7) * 8;       // 0..56 (shorts)
  const int lds_base = wave * 512;       // wave-uniform (shorts)

  // prologue: stage k0=0 into buffer 0
  for (int i = 0; i < 4; ++i) {
    int row = s_row + i * 32;
    GLDS16(A + (size_t)(bm + row) * K + s_col, &As[0][i * 2048 + lds_base]);
    GLDS16(BT + (size_t)(bn + row) * K + s_col, &Bs[0][i * 2048 + lds_base]);
  }
  __syncthreads();                       // drains prologue stage

  int cur = 0;
  for (int t = 0; t < 16; ++t) {
    // stage NEXT k-tile first (loads fly during compute below)
    if (t < 15) {
      const int k0 = (t + 1) * 64;
      for (int i = 0; i < 4; ++i) {
        int row = s_row + i * 32;
        GLDS16(A + (size_t)(bm + row) * K + k0 + s_col, &As[cur ^ 1][i * 2048 + lds_base]);
        GLDS16(BT + (size_t)(bn + row) * K + k0 + s_col, &Bs[cur ^ 1][i * 2048 + lds_base]);
      }
    }
    // compute current tile
    for (int ks = 0; ks < 2; ++ks) {
      bf16x8 af[4], bfr[4];
      for (int mi = 0; mi < 4; ++mi)
        af[mi] = *(const bf16x8*)(&As[cur][(wm + mi * 16 + l16) * 64 + ks * 32 + quad * 8]);
      for (int ni = 0; ni < 4; ++ni)
        bfr[ni] = *(const bf16x8*)(&Bs[cur][(wn + ni * 16 + l16) * 64 + ks * 32 + quad * 8]);
      for (int mi = 0; mi < 4; ++mi)
        for (int ni = 0; ni < 4; ++ni)
          acc[mi][ni] = __builtin_amdgcn_mfma_f32_16x16x32_bf16(af[mi], bfr[ni], acc[mi][ni], 0, 0, 0);
    }
    __syncthreads();                     // drains next-tile stage; guards buffer reuse
    cur ^= 1;
  }

  for (int ni = 0; ni < 4; ++ni) {
    int col = bn + wn + ni * 16 + l16;
    float bv = bias[col];
    for (int mi = 0; mi < 4; ++mi) {
      int row0 = bm + wm + mi * 16 + quad * 4;   // C row = quad*4+reg
      for (int r = 0; r < 4; ++r) {
        int row = row0 + r;
        float fv = acc[mi][ni][r] + bv;
        if (mode == 2) ((float*)Cp)[(size_t)row * N + col] = fv;
        else           ((short*)Cp)[(size_t)row * N + col] = f2bf(fv);
      }
    }
  }
}

__global__ __launch_bounds__(256) void gemm_bt16(
    const short* __restrict__ A, const short* __restrict__ BT,
    const float* __restrict__ bias, void* __restrict__ Cp, int mode)
{
  gemm_body(A, BT, bias, Cp, mode);
}

// combined Q/K/V projection: grid.z selects which GEMM
__global__ __launch_bounds__(256) void gemm_qkv(QkvArgs a)
{
  const int z = blockIdx.z;
  gemm_body(a.A[z], a.B[z], a.bias[z], a.C[z], 0);
}

// ---------- fused attention over [G=128,T=1024,D=64] ----------
// 2-chunk (2 x 512) s-loop, f16-packed sig, launch_bounds(256,2):
// unified regs <= 256/wave (demand ~230 after packing -> no spill) AND
// LDS 34.3KB (R2/R3's footprint -> 2 blocks/CU) AND grid 512 (hg-split)
// => first genuinely co-resident 2-waves/SIMD run at ~R9 VMEM density.
// Per chunk: 4 waves score 128-wide strips (8 tiles, K prefetch 4-deep,
// raw e^x -> Plds) | B1 | d-split PV accumulates | B2. After 2 chunks:
// rsum reduce, red dbuf'd by head parity | B3 | scale + ctx write.
// Epilogue: hg0 -> f32 attn_post; hg1 -> bf16 partial (add_post sums).
__global__ __launch_bounds__(256, 2) void attn_fused14(
    const short* __restrict__ Qp, const short* __restrict__ Kp,
    const short* __restrict__ VpT,               // [g][d][t]
    short* __restrict__ ctx,                     // [g][t][d] flat (bf16)
    float* __restrict__ attn_post,               // [b][t][s] FP32 (hg0 partial)
    short* __restrict__ part)                    // [b][t][s] bf16 (hg1 partial)
{
  __shared__ short Plds[32][520];                // 33.3KB (chunk of 512 + pad)
  __shared__ float red[2][32][4];                // dbuf'd by head parity

  const int tid = threadIdx.x;
  const int wave = tid >> 6, lane = tid & 63;
  const int quad = lane >> 4, l16 = lane & 15;
  // XCD-chunk remap (T1): b == orig&7  (XCD i <- batch i)
  const int orig = blockIdx.x;                   // 0..511
  const int b = orig & 7;
  const int hg = (orig >> 3) & 1;                // head group (8 heads)
  const int t0 = (orig >> 4) * 32;               // 32-row t-tile
  const int wbase = wave * 128;                  // wave's strip within a chunk

  h2 sig[2][16][2];                              // [tt][c*8+tile][rpair], f16x2
#pragma unroll
  for (int tt = 0; tt < 2; ++tt)
    for (int k = 0; k < 16; ++k)
      for (int p = 0; p < 2; ++p) sig[tt][k][p] = h2{(_Float16)0.f, (_Float16)0.f};

  for (int h = hg * 8; h < hg * 8 + 8; ++h) {
    const int g = b * 16 + h;
    const short* Qg = Qp + (size_t)g * 65536;
    const short* Kg = Kp + (size_t)g * 65536;
    const short* Vg = VpT + (size_t)g * 65536;
    const short* Vw = Vg + (size_t)(wave * 16 + l16) * 1024;

    bf16x8 aq[2][2];
#pragma unroll
    for (int tt = 0; tt < 2; ++tt) {
      aq[tt][0] = *(const bf16x8*)(Qg + (t0 + tt * 16 + l16) * 64 + quad * 8);
      aq[tt][1] = *(const bf16x8*)(Qg + (t0 + tt * 16 + l16) * 64 + 32 + quad * 8);
    }

    float rsum[2][4] = {};
    f32x4 acc[2][2] = {};                        // PV accumulators, [tt][parity]

#pragma unroll
    for (int c = 0; c < 2; ++c) {
      const int sb = c * 512 + wbase;            // wave's 128-wide strip

      // ---- score: 8 s-tiles, K prefetched 4 tiles deep ----
      bf16x8 kb0[4], kb1[4];
#pragma unroll
      for (int t = 0; t < 4; ++t) {
        int s = sb + t * 16;
        kb0[t] = *(const bf16x8*)(Kg + (s + l16) * 64 + quad * 8);
        kb1[t] = *(const bf16x8*)(Kg + (s + l16) * 64 + 32 + quad * 8);
      }
#pragma unroll
      for (int tile = 0; tile < 8; ++tile) {
        const int slot = tile & 3;
        bf16x8 bk0 = kb0[slot], bk1 = kb1[slot];
        if (tile < 4) {
          int s = sb + (tile + 4) * 16;
          kb0[slot] = *(const bf16x8*)(Kg + (s + l16) * 64 + quad * 8);
          kb1[slot] = *(const bf16x8*)(Kg + (s + l16) * 64 + 32 + quad * 8);
        }
#pragma unroll
        for (int tt = 0; tt < 2; ++tt) {
          f32x4 cc = {0.f, 0.f, 0.f, 0.f};
          cc = __builtin_amdgcn_mfma_f32_16x16x32_bf16(aq[tt][0], bk0, cc, 0, 0, 0);
          cc = __builtin_amdgcn_mfma_f32_16x16x32_bf16(aq[tt][1], bk1, cc, 0, 0, 0);
          float e[4];
#pragma unroll
          for (int r = 0; r < 4; ++r) {
            e[r] = exp2_hw(cc[r] * L2E_HALF);    // e^(score*0.5)
            rsum[tt][r] += e[r];
            Plds[tt * 16 + quad * 4 + r][wbase + tile * 16 + l16] = f2bf_rhu(e[r]);
          }
          // sigmoid = e/(1+e), accumulate packed f16 (proven R3)
          float s0 = e[0] * __builtin_amdgcn_rcpf(1.f + e[0]);
          float s1 = e[1] * __builtin_amdgcn_rcpf(1.f + e[1]);
          float s2 = e[2] * __builtin_amdgcn_rcpf(1.f + e[2]);
          float s3 = e[3] * __builtin_amdgcn_rcpf(1.f + e[3]);
          sig[tt][c * 8 + tile][0] += h2{(_Float16)s0, (_Float16)s1};
          sig[tt][c * 8 + tile][1] += h2{(_Float16)s2, (_Float16)s3};
        }
      }
      __syncthreads();                           // B1: chunk's Plds ready

      // ---- PV for this chunk: wave owns d-cols [wave*16,+16) ----
#pragma unroll
      for (int sl = 0; sl < 16; ++sl) {
        bf16x8 v  = *(const bf16x8*)(Vw + c * 512 + sl * 32 + quad * 8);
        bf16x8 p0 = *(const bf16x8*)(&Plds[l16][sl * 32 + quad * 8]);
        bf16x8 p1 = *(const bf16x8*)(&Plds[16 + l16][sl * 32 + quad * 8]);
        acc[0][sl & 1] = __builtin_amdgcn_mfma_f32_16x16x32_bf16(p0, v, acc[0][sl & 1], 0, 0, 0);
        acc[1][sl & 1] = __builtin_amdgcn_mfma_f32_16x16x32_bf16(p1, v, acc[1][sl & 1], 0, 0, 0);
      }
      __syncthreads();                           // B2: Plds free for next chunk
    }

    // ---- rowsum reduce + normalize + ctx write ----
#pragma unroll
    for (int tt = 0; tt < 2; ++tt)
      for (int r = 0; r < 4; ++r)
        for (int mask = 1; mask < 16; mask <<= 1)
          rsum[tt][r] += __shfl_xor(rsum[tt][r], mask, 64);
    if (l16 == 0)
#pragma unroll
      for (int tt = 0; tt < 2; ++tt)
        for (int r = 0; r < 4; ++r)
          red[h & 1][tt * 16 + quad * 4 + r][wave] = rsum[tt][r];
    __syncthreads();                             // B3: red visible

    short* ctxg = ctx + (size_t)g * 65536 + t0 * 64;
#pragma unroll
    for (int tt = 0; tt < 2; ++tt)
      for (int r = 0; r < 4; ++r) {
        int row = tt * 16 + quad * 4 + r;
        float s4 = red[h & 1][row][0] + red[h & 1][row][1]
                 + red[h & 1][row][2] + red[h & 1][row][3];
        float inv = __builtin_amdgcn_rcpf(s4);
        float cval = (acc[tt][0][r] + acc[tt][1][r]) * inv;
        ctxg[row * 64 + wave * 16 + l16] = f2bf(cval);
      }
    // next head's Plds writes (own wave strip) don't conflict with ctx
    // writes (registers/red only); red is parity-double-buffered.
  }

  // epilogue: disjoint plain stores (no atomics, no RMW)
  if (hg == 0) {
    float* ap_out = attn_post + (size_t)b * 1048576 + (size_t)t0 * 1024;
#pragma unroll
    for (int tt = 0; tt < 2; ++tt)
      for (int k = 0; k < 16; ++k) {
        int ci = k >> 3, tile = k & 7;
        int col = ci * 512 + wbase + tile * 16 + l16;
        ap_out[(tt * 16 + quad * 4 + 0) * 1024 + col] = (float)sig[tt][k][0][0] * 0.0625f;
        ap_out[(tt * 16 + quad * 4 + 1) * 1024 + col] = (float)sig[tt][k][0][1] * 0.0625f;
        ap_out[(tt * 16 + quad * 4 + 2) * 1024 + col] = (float)sig[tt][k][1][0] * 0.0625f;
        ap_out[(tt * 16 + quad * 4 + 3) * 1024 + col] = (float)sig[tt][k][1][1] * 0.0625f;
      }
  } else {
    short* pp = part + (size_t)b * 1048576 + (size_t)t0 * 1024;
#pragma unroll
    for (int tt = 0; tt < 2; ++tt)
      for (int k = 0; k < 16; ++k) {
        int ci = k >> 3, tile = k & 7;
        int col = ci * 512 + wbase + tile * 16 + l16;
        pp[(tt * 16 + quad * 4 + 0) * 1024 + col] = f2bf((float)sig[tt][k][0][0] * 0.0625f);
        pp[(tt * 16 + quad * 4 + 1) * 1024 + col] = f2bf((float)sig[tt][k][0][1] * 0.0625f);
        pp[(tt * 16 + quad * 4 + 2) * 1024 + col] = f2bf((float)sig[tt][k][1][0] * 0.0625f);
        pp[(tt * 16 + quad * 4 + 3) * 1024 + col] = f2bf((float)sig[tt][k][1][1] * 0.0625f);
      }
  }
}

extern "C" void kernel_launch(void* const* d_in, const int* in_sizes, int n_in,
                              void* d_out, int out_size, void* d_ws, size_t ws_size,
                              hipStream_t stream) {
  const float* query = (const float*)d_in[0];
  const float* key   = (const float*)d_in[1];
  const float* value = (const float*)d_in[2];
  const float* Wq = (const float*)d_in[3]; const float* bq = (const float*)d_in[4];
  const float* Wk = (const float*)d_in[5]; const float* bk = (const float*)d_in[6];
  const float* Wv = (const float*)d_in[7]; const float* bv = (const float*)d_in[8];
  const float* Wo = (const float*)d_in[9]; const float* bo = (const float*)d_in[10];

  float* out0 = (float*)d_out;              // [8,1024,1024] fp32
  float* attn_post = out0 + (8u << 20);     // [8,1024,1024] fp32

  // common workspace head: 4 x 1M weightT + 3 x 8M (Qp,Kp,VpT)
  short* WqT = (short*)d_ws;
  short* WkT = WqT + (1u << 20);
  short* WvT = WkT + (1u << 20);
  short* WoT = WvT + (1u << 20);
  short* Qp  = WoT + (1u << 20);
  short* Kp  = Qp + (8u << 20);
  short* VpT = Kp + (8u << 20);

  dim3 blk(256);
  dim3 ggrid(64, 8);                        // 512 blocks, 128x128 tiles
  const size_t NEED_BIG = (size_t)(60u << 20) * 2;   // 120 MiB

  convt4<<<dim3(16, 16, 4), blk, 0, stream>>>(
      Ptr4{{Wq, Wk, Wv, Wo}, {WqT, WkT, WvT, WoT}});

  short* ctx;
  short* part;                              // bf16 hg1 sigmoid partial (16 MB)
  if (ws_size >= NEED_BIG) {
    // big layout: + Xq,Xk,Xv (3 x 8M) + Vflat (8M) = 60M shorts total
    short* Xq = VpT + (8u << 20);
    short* Xk = Xq + (8u << 20);
    short* Xv = Xk + (8u << 20);
    short* Vflat = Xv + (8u << 20);
    ctx = Xq;                                      // dead after qkv GEMM
    part = Vflat;                                  // dead after transp_v

    cvt3<<<dim3(4096, 1, 3), blk, 0, stream>>>(Ptr3{{query, key, value}, {Xq, Xk, Xv}});
    gemm_qkv<<<dim3(64, 8, 3), blk, 0, stream>>>(
        QkvArgs{{Xq, Xk, Xv}, {WqT, WkT, WvT}, {bq, bk, bv}, {Qp, Kp, Vflat}});
    transp_v<<<dim3(16, 128), blk, 0, stream>>>(Vflat, VpT);
  } else {
    // small layout (88 MB, proven): Xin (8M) + Vflat (8M), sequential
    short* Xin = VpT + (8u << 20);
    short* Vflat = Xin + (8u << 20);
    ctx = Xin;
    part = Vflat;                                  // dead after transp_v

    cvt3<<<dim3(4096, 1, 1), blk, 0, stream>>>(Ptr3{{query, query, query}, {Xin, Xin, Xin}});
    gemm_bt16<<<ggrid, blk, 0, stream>>>(Xin, WqT, bq, Qp, 0);
    cvt3<<<dim3(4096, 1, 1), blk, 0, stream>>>(Ptr3{{key, key, key}, {Xin, Xin, Xin}});
    gemm_bt16<<<ggrid, blk, 0, stream>>>(Xin, WkT, bk, Kp, 0);
    cvt3<<<dim3(4096, 1, 1), blk, 0, stream>>>(Ptr3{{value, value, value}, {Xin, Xin, Xin}});
    gemm_bt16<<<ggrid, blk, 0, stream>>>(Xin, WvT, bv, Vflat, 0);
    transp_v<<<dim3(16, 128), blk, 0, stream>>>(Vflat, VpT);
  }

  attn_fused14<<<dim3(512), blk, 0, stream>>>(Qp, Kp, VpT, ctx, attn_post, part);
  add_post<<<dim3(4096), blk, 0, stream>>>(attn_post, part);
  gemm_bt16<<<ggrid, blk, 0, stream>>>(ctx, WoT, bo, out0, 2);
}

// Round 17
// 456.907 us; speedup vs baseline: 1.2276x; 1.0477x over previous
//
#include <hip/hip_runtime.h>

// B=8, S=1024, MD=1024, H=16, D=64. SCALE = (64//16)^-0.5 = 0.5.
// Inputs fp32, OUTPUTS fp32. Internal pipeline bf16 MFMA, fp32 accumulate.
// torch .view(B*H,-1,D) = flat row-major reinterpretation: attention over
// [G=128][T=1024][D=64] with flat pointer math.
//
// FINAL (R17): best-measured assembly. 16 rounds of falsification closed
// every lever: attn is VMEM-instruction-density bound (R9's t=32 d-split
// structure is density-optimal: each K/V byte loaded once/block, 16B/lane
// max width; t=64 exceeds the 256-reg budget -> spill); TLP conclusively
// null (R16: clean 2-blocks/CU co-residency, no spill, = 1-block perf);
// occupancy/ILP/barriers/locality all exonerated with counter evidence.
// GEMMs sit on the m97-structure plateau for this shape (320 TF; retile /
// swizzle axes / 2-phase each <=4%; 8-phase template needs >=4 blocks/CU
// which N=1024 can't feed). Config: R9 attn_fused8 + R12 GEMM (M-panel
// XCD swizzle + 2-phase dbuf) + merged convt4/cvt3/gemm_qkv dispatches.

typedef __attribute__((ext_vector_type(8))) short bf16x8;
typedef __attribute__((ext_vector_type(4))) float f32x4;

static __device__ __forceinline__ short f2bf(float f) {
  union { float f; unsigned u; } v; v.f = f;
  unsigned lsb = (v.u >> 16) & 1u;
  v.u += 0x7fffu + lsb;
  return (short)(v.u >> 16);
}

// round-half-up bf16 (2 ops); fine for positive e^x values
static __device__ __forceinline__ short f2bf_rhu(float f) {
  union { float f; unsigned u; } v; v.f = f;
  v.u += 0x8000u;
  return (short)(v.u >> 16);
}

// hardware 2^x
static __device__ __forceinline__ float exp2_hw(float x) {
  float r;
  asm("v_exp_f32 %0, %1" : "=v"(r) : "v"(x));
  return r;
}

#define L2E_HALF 0.72134752f   /* 0.5 * log2(e) : e^(score*0.5) = 2^(score*this) */

// async global->LDS, 16B per lane; LDS dest = wave-uniform base + lane*16
#define GLDS16(gp, lp) __builtin_amdgcn_global_load_lds( \
    (const __attribute__((address_space(1))) void*)(gp), \
    (__attribute__((address_space(3))) void*)(lp), 16, 0, 0)

struct Ptr4 { const float* s[4]; short* d[4]; };
struct Ptr3 { const float* s[3]; short* d[3]; };
struct QkvArgs { const short* A[3]; const short* B[3]; const float* bias[3]; short* C[3]; };

// ---------- fp32 W[k][n] -> bf16 WT[n][k], 64x64 tiles; z selects matrix ----
__global__ __launch_bounds__(256) void convt4(Ptr4 a)
{
  const float* __restrict__ src = a.s[blockIdx.z];
  short* __restrict__ dst = a.d[blockIdx.z];
  __shared__ float T[64][65];
  const int tid = threadIdx.x;
  const int c0 = blockIdx.x * 64, r0 = blockIdx.y * 64;
  {
    const int rr = tid >> 4, cc = (tid & 15) * 4;
    for (int i = 0; i < 4; ++i) {
      int row = rr + i * 16;
      const float4 v = *(const float4*)(src + (size_t)(r0 + row) * 1024 + c0 + cc);
      T[row][cc] = v.x; T[row][cc + 1] = v.y; T[row][cc + 2] = v.z; T[row][cc + 3] = v.w;
    }
  }
  __syncthreads();
  {
    const int rr = tid >> 3, cc = (tid & 7) * 8;
    for (int i = 0; i < 2; ++i) {
      int row = rr + i * 32;             // dst row within tile (= src col)
      bf16x8 v;
      for (int j = 0; j < 8; ++j) v[j] = f2bf(T[cc + j][row]);
      *(bf16x8*)(dst + (size_t)(c0 + row) * 1024 + r0 + cc) = v;
    }
  }
}

// ---------- fp32 -> bf16 elementwise; z selects tensor ----------
__global__ __launch_bounds__(256) void cvt3(Ptr3 a)
{
  const float* __restrict__ src = a.s[blockIdx.z];
  short* __restrict__ dst = a.d[blockIdx.z];
  const size_t i = ((size_t)blockIdx.x * 256 + threadIdx.x) * 8;
  const float4 v0 = *(const float4*)(src + i);
  const float4 v1 = *(const float4*)(src + i + 4);
  bf16x8 o;
  o[0] = f2bf(v0.x); o[1] = f2bf(v0.y); o[2] = f2bf(v0.z); o[3] = f2bf(v0.w);
  o[4] = f2bf(v1.x); o[5] = f2bf(v1.y); o[6] = f2bf(v1.z); o[7] = f2bf(v1.w);
  *(bf16x8*)(dst + i) = o;
}

// ---------- per-g 64x64 bf16 tile transpose: V[g][t][d] -> VpT[g][d][t] ----
__global__ __launch_bounds__(256) void transp_v(
    const short* __restrict__ src, short* __restrict__ dst)
{
  __shared__ short T[64][72];
  const int g = blockIdx.y, t0 = blockIdx.x * 64;
  const short* s = src + (size_t)g * 65536 + (size_t)t0 * 64;
  short* d = dst + (size_t)g * 65536 + t0;
  const int r = threadIdx.x >> 3, c = (threadIdx.x & 7) * 8;
  for (int i = 0; i < 2; ++i) {
    bf16x8 v = *(const bf16x8*)(s + (size_t)(r + i * 32) * 64 + c);
    *(bf16x8*)(&T[r + i * 32][c]) = v;
  }
  __syncthreads();
  for (int i = 0; i < 2; ++i) {
    int dr = r + i * 32;                 // d index
    bf16x8 v;
    for (int j = 0; j < 8; ++j) v[j] = T[c + j][dr];
    *(bf16x8*)(d + (size_t)dr * 1024 + c) = v;
  }
}

// ---------- GEMM body: C[8192,1024] = A[8192,1024](bf16) * BT[1024,1024]^T + bias
// 128x128 tiles, 512 blocks. M-panel XCD swizzle: xcd = lin&7 owns M-tiles
// [8*xcd, 8*xcd+8) x all 8 N-tiles -> A-panel (2MB) + B (2MB) L2-resident
// per XCD. Bijective. 2-phase pipeline: dbuf LDS, stage t+1 before compute
// of t, one barrier per k-step (vmcnt drain lands after MFMAs).
static __device__ __forceinline__ void gemm_body(
    const short* __restrict__ A, const short* __restrict__ BT,
    const float* __restrict__ bias, void* __restrict__ Cp, int mode)
{
  __shared__ short As[2][128 * 64];
  __shared__ short Bs[2][128 * 64];
  const int K = 1024, N = 1024;
  const int tid = threadIdx.x;
  const int lane = tid & 63, wave = tid >> 6;
  const int quad = lane >> 4, l16 = lane & 15;
  const int wm = (wave & 1) * 64, wn = (wave >> 1) * 64;
  const int lin = blockIdx.y * 64 + blockIdx.x;
  const int xcd = lin & 7, idx = lin >> 3;       // idx 0..63
  const int bx = xcd * 8 + (idx & 7);            // M-tile 0..63
  const int by = idx >> 3;                       // N-tile 0..7
  const int bm = bx * 128, bn = by * 128;

  f32x4 acc[4][4] = {};

  const int s_row = tid >> 3;            // 0..31
  const int s_col = (tid & 7) * 8;       // 0..56 (shorts)
  const int lds_base = wave * 512;       // wave-uniform (shorts)

  // prologue: stage k0=0 into buffer 0
  for (int i = 0; i < 4; ++i) {
    int row = s_row + i * 32;
    GLDS16(A + (size_t)(bm + row) * K + s_col, &As[0][i * 2048 + lds_base]);
    GLDS16(BT + (size_t)(bn + row) * K + s_col, &Bs[0][i * 2048 + lds_base]);
  }
  __syncthreads();                       // drains prologue stage

  int cur = 0;
  for (int t = 0; t < 16; ++t) {
    // stage NEXT k-tile first (loads fly during compute below)
    if (t < 15) {
      const int k0 = (t + 1) * 64;
      for (int i = 0; i < 4; ++i) {
        int row = s_row + i * 32;
        GLDS16(A + (size_t)(bm + row) * K + k0 + s_col, &As[cur ^ 1][i * 2048 + lds_base]);
        GLDS16(BT + (size_t)(bn + row) * K + k0 + s_col, &Bs[cur ^ 1][i * 2048 + lds_base]);
      }
    }
    // compute current tile
    for (int ks = 0; ks < 2; ++ks) {
      bf16x8 af[4], bfr[4];
      for (int mi = 0; mi < 4; ++mi)
        af[mi] = *(const bf16x8*)(&As[cur][(wm + mi * 16 + l16) * 64 + ks * 32 + quad * 8]);
      for (int ni = 0; ni < 4; ++ni)
        bfr[ni] = *(const bf16x8*)(&Bs[cur][(wn + ni * 16 + l16) * 64 + ks * 32 + quad * 8]);
      for (int mi = 0; mi < 4; ++mi)
        for (int ni = 0; ni < 4; ++ni)
          acc[mi][ni] = __builtin_amdgcn_mfma_f32_16x16x32_bf16(af[mi], bfr[ni], acc[mi][ni], 0, 0, 0);
    }
    __syncthreads();                     // drains next-tile stage; guards buffer reuse
    cur ^= 1;
  }

  for (int ni = 0; ni < 4; ++ni) {
    int col = bn + wn + ni * 16 + l16;
    float bv = bias[col];
    for (int mi = 0; mi < 4; ++mi) {
      int row0 = bm + wm + mi * 16 + quad * 4;   // C row = quad*4+reg
      for (int r = 0; r < 4; ++r) {
        int row = row0 + r;
        float fv = acc[mi][ni][r] + bv;
        if (mode == 2) ((float*)Cp)[(size_t)row * N + col] = fv;
        else           ((short*)Cp)[(size_t)row * N + col] = f2bf(fv);
      }
    }
  }
}

__global__ __launch_bounds__(256) void gemm_bt16(
    const short* __restrict__ A, const short* __restrict__ BT,
    const float* __restrict__ bias, void* __restrict__ Cp, int mode)
{
  gemm_body(A, BT, bias, Cp, mode);
}

// combined Q/K/V projection: grid.z selects which GEMM
__global__ __launch_bounds__(256) void gemm_qkv(QkvArgs a)
{
  const int z = blockIdx.z;
  gemm_body(a.A[z], a.B[z], a.bias[z], a.C[z], 0);
}

// ---------- fused attention over [G=128,T=1024,D=64] (R9 structure) ----------
// block = (b via XCD remap, 32-row t-tile); grid 256 = 1 block/CU.
// Score: 4 waves x s=256 strips; each K fragment pair feeds 2 t-tiles
// (4 MFMA). Raw e^x -> Plds (deferred normalization); sig in regs.
// B1. PV: d-split, wave owns 16 d-cols, full s=1024, V fragment shared by
// both t-tiles; scale by 1/rowsum from red; ctx written straight to
// global. B2 guards Plds reuse. This is the VMEM-density-optimal member
// of the family (each K/V byte loaded once per block, 16B/lane).
__global__ __launch_bounds__(256, 1) void attn_fused8(
    const short* __restrict__ Qp, const short* __restrict__ Kp,
    const short* __restrict__ VpT,               // [g][d][t]
    short* __restrict__ ctx,                     // [g][t][d] flat (bf16)
    float* __restrict__ attn_post)               // [b][t][s] FP32
{
  __shared__ short Plds[32][1032];               // 66KB
  __shared__ float red[32][4];

  const int tid = threadIdx.x;
  const int wave = tid >> 6, lane = tid & 63;
  const int quad = lane >> 4, l16 = lane & 15;
  // XCD-chunk remap (T1): b == orig&7  (XCD i <- batch i)
  const int orig = blockIdx.x;                   // 0..255
  const int b = orig & 7;
  const int t0 = (orig >> 3) * 32;               // 32-row t-tile
  const int sbase = wave * 256;

  float sig[2][16][4] = {};                      // [tt][tile][r]

  for (int h = 0; h < 16; ++h) {
    const int g = b * 16 + h;
    const short* Qg = Qp + (size_t)g * 65536;
    const short* Kg = Kp + (size_t)g * 65536;
    const short* Vg = VpT + (size_t)g * 65536;

    bf16x8 aq[2][2];
#pragma unroll
    for (int tt = 0; tt < 2; ++tt) {
      aq[tt][0] = *(const bf16x8*)(Qg + (t0 + tt * 16 + l16) * 64 + quad * 8);
      aq[tt][1] = *(const bf16x8*)(Qg + (t0 + tt * 16 + l16) * 64 + 32 + quad * 8);
    }

    float rsum[2][4] = {};

    // ---- QK^T score loop: 16 s-tiles, K prefetched 4 tiles deep ----
    bf16x8 kb0[4], kb1[4];
#pragma unroll
    for (int t = 0; t < 4; ++t) {
      int s = sbase + t * 16;
      kb0[t] = *(const bf16x8*)(Kg + (s + l16) * 64 + quad * 8);
      kb1[t] = *(const bf16x8*)(Kg + (s + l16) * 64 + 32 + quad * 8);
    }
#pragma unroll
    for (int tile = 0; tile < 16; ++tile) {
      const int slot = tile & 3;
      bf16x8 bk0 = kb0[slot], bk1 = kb1[slot];
      if (tile < 12) {
        int s = sbase + (tile + 4) * 16;
        kb0[slot] = *(const bf16x8*)(Kg + (s + l16) * 64 + quad * 8);
        kb1[slot] = *(const bf16x8*)(Kg + (s + l16) * 64 + 32 + quad * 8);
      }
#pragma unroll
      for (int tt = 0; tt < 2; ++tt) {
        f32x4 c = {0.f, 0.f, 0.f, 0.f};
        c = __builtin_amdgcn_mfma_f32_16x16x32_bf16(aq[tt][0], bk0, c, 0, 0, 0);
        c = __builtin_amdgcn_mfma_f32_16x16x32_bf16(aq[tt][1], bk1, c, 0, 0, 0);
#pragma unroll
        for (int r = 0; r < 4; ++r) {
          float e = exp2_hw(c[r] * L2E_HALF);    // e^(score*0.5)
          rsum[tt][r] += e;
          Plds[tt * 16 + quad * 4 + r][sbase + tile * 16 + l16] = f2bf_rhu(e);
          sig[tt][tile][r] += e * __builtin_amdgcn_rcpf(1.f + e);   // sigmoid
        }
      }
    }
#pragma unroll
    for (int tt = 0; tt < 2; ++tt)
      for (int r = 0; r < 4; ++r)
        for (int mask = 1; mask < 16; mask <<= 1)
          rsum[tt][r] += __shfl_xor(rsum[tt][r], mask, 64);
    if (l16 == 0)
#pragma unroll
      for (int tt = 0; tt < 2; ++tt)
        for (int r = 0; r < 4; ++r)
          red[tt * 16 + quad * 4 + r][wave] = rsum[tt][r];
    __syncthreads();                             // B1: Plds + red visible

    // ---- PV: wave owns d-cols [wave*16, wave*16+16), full s=1024 ----
    // A = P[t-within-tile = l16][s-slice], B = V^T[d = wave*16+l16][s-slice].
    const short* Vw = Vg + (size_t)(wave * 16 + l16) * 1024;
    f32x4 acc[2][2] = {};                        // [tt][parity]
#pragma unroll
    for (int sl = 0; sl < 32; ++sl) {
      bf16x8 v  = *(const bf16x8*)(Vw + sl * 32 + quad * 8);
      bf16x8 p0 = *(const bf16x8*)(&Plds[l16][sl * 32 + quad * 8]);
      bf16x8 p1 = *(const bf16x8*)(&Plds[16 + l16][sl * 32 + quad * 8]);
      acc[0][sl & 1] = __builtin_amdgcn_mfma_f32_16x16x32_bf16(p0, v, acc[0][sl & 1], 0, 0, 0);
      acc[1][sl & 1] = __builtin_amdgcn_mfma_f32_16x16x32_bf16(p1, v, acc[1][sl & 1], 0, 0, 0);
    }

    // normalize by 1/rowsum and write ctx directly
    short* ctxg = ctx + (size_t)g * 65536 + t0 * 64;
#pragma unroll
    for (int tt = 0; tt < 2; ++tt)
      for (int r = 0; r < 4; ++r) {
        int row = tt * 16 + quad * 4 + r;
        float s4 = red[row][0] + red[row][1] + red[row][2] + red[row][3];
        float inv = __builtin_amdgcn_rcpf(s4);
        float cval = (acc[tt][0][r] + acc[tt][1][r]) * inv;
        ctxg[row * 64 + wave * 16 + l16] = f2bf(cval);
      }
    __syncthreads();                             // B2: Plds/red free for next head
  }

  float* ap_out = attn_post + (size_t)b * 1048576 + (size_t)t0 * 1024;
#pragma unroll
  for (int tt = 0; tt < 2; ++tt)
    for (int tile = 0; tile < 16; ++tile)
      for (int r = 0; r < 4; ++r)
        ap_out[(tt * 16 + quad * 4 + r) * 1024 + sbase + tile * 16 + l16] =
            sig[tt][tile][r] * 0.0625f;
}

extern "C" void kernel_launch(void* const* d_in, const int* in_sizes, int n_in,
                              void* d_out, int out_size, void* d_ws, size_t ws_size,
                              hipStream_t stream) {
  const float* query = (const float*)d_in[0];
  const float* key   = (const float*)d_in[1];
  const float* value = (const float*)d_in[2];
  const float* Wq = (const float*)d_in[3]; const float* bq = (const float*)d_in[4];
  const float* Wk = (const float*)d_in[5]; const float* bk = (const float*)d_in[6];
  const float* Wv = (const float*)d_in[7]; const float* bv = (const float*)d_in[8];
  const float* Wo = (const float*)d_in[9]; const float* bo = (const float*)d_in[10];

  float* out0 = (float*)d_out;              // [8,1024,1024] fp32
  float* attn_post = out0 + (8u << 20);     // [8,1024,1024] fp32

  // common workspace head: 4 x 1M weightT + 3 x 8M (Qp,Kp,VpT)
  short* WqT = (short*)d_ws;
  short* WkT = WqT + (1u << 20);
  short* WvT = WkT + (1u << 20);
  short* WoT = WvT + (1u << 20);
  short* Qp  = WoT + (1u << 20);
  short* Kp  = Qp + (8u << 20);
  short* VpT = Kp + (8u << 20);

  dim3 blk(256);
  dim3 ggrid(64, 8);                        // 512 blocks, 128x128 tiles
  const size_t NEED_BIG = (size_t)(60u << 20) * 2;   // 120 MiB

  convt4<<<dim3(16, 16, 4), blk, 0, stream>>>(
      Ptr4{{Wq, Wk, Wv, Wo}, {WqT, WkT, WvT, WoT}});

  short* ctx;
  if (ws_size >= NEED_BIG) {
    // big layout: + Xq,Xk,Xv (3 x 8M) + Vflat (8M) = 60M shorts total
    short* Xq = VpT + (8u << 20);
    short* Xk = Xq + (8u << 20);
    short* Xv = Xk + (8u << 20);
    short* Vflat = Xv + (8u << 20);
    ctx = Xq;                                      // dead after qkv GEMM

    cvt3<<<dim3(4096, 1, 3), blk, 0, stream>>>(Ptr3{{query, key, value}, {Xq, Xk, Xv}});
    gemm_qkv<<<dim3(64, 8, 3), blk, 0, stream>>>(
        QkvArgs{{Xq, Xk, Xv}, {WqT, WkT, WvT}, {bq, bk, bv}, {Qp, Kp, Vflat}});
    transp_v<<<dim3(16, 128), blk, 0, stream>>>(Vflat, VpT);
  } else {
    // small layout (88 MB, proven): Xin (8M) + Vflat (8M), sequential
    short* Xin = VpT + (8u << 20);
    short* Vflat = Xin + (8u << 20);
    ctx = Xin;

    cvt3<<<dim3(4096, 1, 1), blk, 0, stream>>>(Ptr3{{query, query, query}, {Xin, Xin, Xin}});
    gemm_bt16<<<ggrid, blk, 0, stream>>>(Xin, WqT, bq, Qp, 0);
    cvt3<<<dim3(4096, 1, 1), blk, 0, stream>>>(Ptr3{{key, key, key}, {Xin, Xin, Xin}});
    gemm_bt16<<<ggrid, blk, 0, stream>>>(Xin, WkT, bk, Kp, 0);
    cvt3<<<dim3(4096, 1, 1), blk, 0, stream>>>(Ptr3{{value, value, value}, {Xin, Xin, Xin}});
    gemm_bt16<<<ggrid, blk, 0, stream>>>(Xin, WvT, bv, Vflat, 0);
    transp_v<<<dim3(16, 128), blk, 0, stream>>>(Vflat, VpT);
  }

  attn_fused8<<<dim3(256), blk, 0, stream>>>(Qp, Kp, VpT, ctx, attn_post);
  gemm_bt16<<<ggrid, blk, 0, stream>>>(ctx, WoT, bo, out0, 2);
}